// Round 3
// baseline (15372.237 us; speedup 1.0000x reference)
//
#include <hip/hip_runtime.h>

#define NR 4096
#define NT 720
#define TSEC 3600.0f
#define QLB 1e-4f
#define COLS_MAX 32768
#define MAXC 6

// ---------------- CSR build: count ----------------
__global__ void count_kernel(const float* __restrict__ adj, int* __restrict__ cnt) {
    int row = blockIdx.x;
    int lane = threadIdx.x;
    const float* r = adj + (size_t)row * NR;
    int c = 0;
    for (int base = 0; base < NR; base += 64) {
        float v = r[base + lane];
        unsigned long long m = __ballot(v != 0.0f);
        c += __popcll(m);
    }
    if (lane == 0) cnt[row] = c;
}

// ---------------- exclusive scan (single block, 1024 thr, 4/thread) ----------------
__global__ void scan_kernel(const int* __restrict__ cnt, int* __restrict__ rowptr) {
    __shared__ int part[1024];
    int tid = threadIdx.x;
    int base = tid * 4;
    int s0 = cnt[base], s1 = cnt[base + 1], s2 = cnt[base + 2], s3 = cnt[base + 3];
    int tot = s0 + s1 + s2 + s3;
    part[tid] = tot;
    __syncthreads();
    for (int off = 1; off < 1024; off <<= 1) {
        int v = part[tid];
        int add = (tid >= off) ? part[tid - off] : 0;
        __syncthreads();
        part[tid] = v + add;
        __syncthreads();
    }
    int excl = (tid > 0) ? part[tid - 1] : 0;
    rowptr[base]     = excl;
    rowptr[base + 1] = excl + s0;
    rowptr[base + 2] = excl + s0 + s1;
    rowptr[base + 3] = excl + s0 + s1 + s2;
    if (tid == 1023) rowptr[NR] = excl + tot;
}

// ---------------- CSR build: fill ----------------
__global__ void fill_kernel(const float* __restrict__ adj,
                            const int* __restrict__ rowptr, int* __restrict__ cols) {
    int row = blockIdx.x;
    int lane = threadIdx.x;
    const float* r = adj + (size_t)row * NR;
    int wbase = rowptr[row];
    for (int base = 0; base < NR; base += 64) {
        float v = r[base + lane];
        unsigned long long m = __ballot(v != 0.0f);
        if (v != 0.0f) {
            int pos = __popcll(m & ((1ull << lane) - 1ull));
            cols[wbase + pos] = base + lane;
        }
        wbase += __popcll(m);
    }
}

// ---------------- DAG levels (monotone Jacobi to fixpoint) ----------------
__global__ void level_kernel(const int* __restrict__ rowptr,
                             const int* __restrict__ cols, int* __restrict__ level_g) {
    __shared__ int lev[NR];
    __shared__ int changed;
    int tid = threadIdx.x;
#pragma unroll
    for (int k = 0; k < 4; k++) lev[tid + k * 1024] = 0;
    __syncthreads();
    for (int iter = 0; iter < NR; ++iter) {
        if (tid == 0) changed = 0;
        __syncthreads();
#pragma unroll
        for (int k = 0; k < 4; k++) {
            int i = tid + k * 1024;
            int b0 = rowptr[i], b1 = rowptr[i + 1];
            int m = 0;
            for (int e = b0; e < b1; e++) {
                int l = lev[cols[e]] + 1;
                m = (l > m) ? l : m;
            }
            if (b1 > b0 && m != lev[i]) { lev[i] = m; changed = 1; }
        }
        __syncthreads();
        if (changed == 0) break;
        __syncthreads();
    }
#pragma unroll
    for (int k = 0; k < 4; k++) level_g[tid + k * 1024] = lev[tid + k * 1024];
}

// ---------------- level sort: bitonic on (level<<12 | row), deterministic ----------------
__global__ void sort_kernel(const int* __restrict__ level_g, const int* __restrict__ cnt,
                            int* __restrict__ perm, int* __restrict__ inv,
                            int* __restrict__ lev_p, int* __restrict__ cnt_p,
                            int* __restrict__ meta) {
    __shared__ int keys[NR];
    int tid = threadIdx.x;
#pragma unroll
    for (int m = 0; m < 4; m++) {
        int i = tid + m * 1024;
        keys[i] = (level_g[i] << 12) | i;
    }
    __syncthreads();
    for (int ks = 2; ks <= NR; ks <<= 1) {
        for (int j = ks >> 1; j >= 1; j >>= 1) {
#pragma unroll
            for (int m = 0; m < 4; m++) {
                int i = tid + m * 1024;
                int p = i ^ j;
                if (p > i) {
                    bool up = ((i & ks) == 0);
                    int a = keys[i], b = keys[p];
                    if (up ? (a > b) : (a < b)) { keys[i] = b; keys[p] = a; }
                }
            }
            __syncthreads();
        }
    }
#pragma unroll
    for (int m = 0; m < 4; m++) {
        int p = tid + m * 1024;
        int key = keys[p];
        int row = key & (NR - 1);
        perm[p] = row;
        inv[row] = p;
        lev_p[p] = key >> 12;
        cnt_p[p] = cnt[row];
        if (row == NR - 1) meta[1] = p;       // gage sorted position
        if (p == NR - 1) meta[0] = key >> 12; // max level
    }
}

// ---------------- translate cols to sorted index space ----------------
__global__ void trans_kernel(const int* __restrict__ perm, const int* __restrict__ rowptr,
                             const int* __restrict__ cols, const int* __restrict__ inv,
                             const int* __restrict__ rowptr_p, int* __restrict__ cols_p) {
    int pos = blockIdx.x * blockDim.x + threadIdx.x;
    if (pos >= NR) return;
    int row = perm[pos];
    int b0 = rowptr[row];
    int n = rowptr[row + 1] - b0;
    int w = rowptr_p[pos];
    for (int j = 0; j < n; j++) cols_p[w + j] = inv[cols[b0 + j]];
}

// ---------------- coefficients (written in sorted order) ----------------
__global__ void coef_kernel(const int* __restrict__ perm,
                            const float* __restrict__ raw_n,
                            const float* __restrict__ raw_q,
                            const float* __restrict__ raw_p,
                            const float* __restrict__ width,
                            const float* __restrict__ length,
                            const float* __restrict__ slope,
                            const float* __restrict__ x_storage,
                            float* __restrict__ c1, float* __restrict__ c2,
                            float* __restrict__ c3, float* __restrict__ c4) {
    int pos = blockIdx.x * blockDim.x + threadIdx.x;
    if (pos >= NR) return;
    int i = perm[pos];
    float n   = 0.01f + raw_n[i] * (0.3f - 0.01f);
    float qsp = 1.5f + raw_q[i] * (3.0f - 1.5f);
    float psp = 0.5f + raw_p[i] * (2.0f - 0.5f);
    float s0  = fmaxf(slope[i], 1e-4f);
    float depth = logf(width[i] / psp) / logf(qsp);
    float v = (1.0f / n) * powf(depth, 2.0f / 3.0f) * sqrtf(s0);
    float c = fminf(fmaxf(v, 0.3f), 15.0f) * (5.0f / 3.0f);
    float k = length[i] / c;
    float x = x_storage[0];
    float denom = 2.0f * k * (1.0f - x) + TSEC;
    c1[pos] = (TSEC - 2.0f * k * x) / denom;
    c2[pos] = (TSEC + 2.0f * k * x) / denom;
    c3[pos] = (2.0f * k * (1.0f - x) - TSEC) / denom;
    c4[pos] = 2.0f * TSEC / denom;
}

// ---------------- main routing scan: single workgroup, fused level phases ----------------
// Buffers hold UNCLAMPED solve results (matching solve_triangular); the
// state clamp max(sol, 1e-4) is applied at the consumption points:
//   - cross-timestep gather:  sd += fmax(prev[c], QLB)
//   - own-state term:         dval[k] = fmax(v, QLB)
//   - gage output:            out[t] = fmax(v, QLB)
// Within-timestep gather (sx += cur[c]) stays unclamped, as in the reference.
__global__ __launch_bounds__(1024, 1) void route_kernel(
    const float* __restrict__ qp, const float* __restrict__ c1g,
    const float* __restrict__ c2g, const float* __restrict__ c3g,
    const float* __restrict__ c4g, const int* __restrict__ rowptr_p,
    const int* __restrict__ cols_p, const int* __restrict__ lev_p,
    const int* __restrict__ perm, const int* __restrict__ meta,
    float* __restrict__ out) {
    __shared__ float bufA[NR];
    __shared__ float bufB[NR];
    int tid = threadIdx.x;
    int maxlev = meta[0];
    int gpos = meta[1];

    int LV[4], e0[4], en[4], rowg[4];
    float C1[4], C2[4], C3[4], C4[4], dval[4], qreg[4], qnext[4];
    int colr[4][MAXC];
    int lmin = 1 << 30, lmax = -1;
#pragma unroll
    for (int k = 0; k < 4; k++) {
        int pos = tid * 4 + k;
        LV[k] = lev_p[pos];
        lmin = (LV[k] < lmin) ? LV[k] : lmin;
        lmax = (LV[k] > lmax) ? LV[k] : lmax;
        e0[k] = rowptr_p[pos];
        en[k] = rowptr_p[pos + 1] - e0[k];
        C1[k] = c1g[pos]; C2[k] = c2g[pos]; C3[k] = c3g[pos]; C4[k] = c4g[pos];
        rowg[k] = perm[pos];
#pragma unroll
        for (int j = 0; j < MAXC; j++)
            colr[k][j] = (j < en[k]) ? cols_p[e0[k] + j] : 0;
        float v = qp[rowg[k]];      // d0 = q_prime[0], raw (unclamped)
        dval[k] = v;                // state for t=1 is raw d0
        qreg[k] = v;                // q_lat at t=1 is q_prime[0]
        bufA[pos] = v;
        if (pos == gpos) out[0] = fmaxf(v, QLB);
    }
    __syncthreads();

    float* prev = bufA;
    float* cur  = bufB;
    for (int t = 1; t < NT; t++) {
        if (t < NT - 1) {
#pragma unroll
            for (int k = 0; k < 4; k++)
                qnext[k] = qp[(size_t)t * NR + rowg[k]];
        }
        for (int l = 0; l <= maxlev; l++) {
            if (l >= lmin && l <= lmax) {
#pragma unroll
                for (int k = 0; k < 4; k++) {
                    if (LV[k] == l) {
                        float sd = 0.0f, sx = 0.0f;
                        int n = en[k];
#pragma unroll
                        for (int j = 0; j < MAXC; j++) {
                            if (j < n) {
                                int c = colr[k][j];
                                sd += fmaxf(prev[c], QLB);   // clamped state read
                                sx += cur[c];                // unclamped in-solve read
                            }
                        }
                        for (int j = MAXC; j < n; j++) {   // rare overflow
                            int c = cols_p[e0[k] + j];
                            sd += fmaxf(prev[c], QLB);
                            sx += cur[c];
                        }
                        float v = C2[k] * sd + C3[k] * dval[k]
                                + C4[k] * fmaxf(qreg[k], QLB) + C1[k] * sx;
                        cur[tid * 4 + k] = v;              // unclamped sol
                        dval[k] = fmaxf(v, QLB);           // clamped next-state
                        if (tid * 4 + k == gpos) out[t] = fmaxf(v, QLB);
                    }
                }
            }
            __syncthreads();
        }
        float* tmp = prev; prev = cur; cur = tmp;
#pragma unroll
        for (int k = 0; k < 4; k++) qreg[k] = qnext[k];
    }
}

extern "C" void kernel_launch(void* const* d_in, const int* in_sizes, int n_in,
                              void* d_out, int out_size, void* d_ws, size_t ws_size,
                              hipStream_t stream) {
    const float* q_prime  = (const float*)d_in[0];
    const float* raw_n    = (const float*)d_in[1];
    const float* raw_q    = (const float*)d_in[2];
    const float* raw_p    = (const float*)d_in[3];
    const float* width    = (const float*)d_in[4];
    const float* length   = (const float*)d_in[5];
    const float* slope    = (const float*)d_in[6];
    const float* adj      = (const float*)d_in[7];
    const float* x_stor   = (const float*)d_in[8];
    float* out = (float*)d_out;

    // workspace layout (ints/floats are 4B)
    float* ws_f = (float*)d_ws;
    float* c1p = ws_f;
    float* c2p = ws_f + NR;
    float* c3p = ws_f + 2 * NR;
    float* c4p = ws_f + 3 * NR;
    int* ws_i     = (int*)(ws_f + 4 * NR);
    int* cnt      = ws_i;                    // NR
    int* rowptr   = cnt + NR;                // NR+8
    int* cols     = rowptr + NR + 8;         // COLS_MAX
    int* level    = cols + COLS_MAX;         // NR
    int* perm     = level + NR;              // NR
    int* inv      = perm + NR;               // NR
    int* lev_p    = inv + NR;                // NR
    int* cnt_p    = lev_p + NR;              // NR
    int* rowptr_p = cnt_p + NR;              // NR+8
    int* cols_p   = rowptr_p + NR + 8;       // COLS_MAX
    int* meta     = cols_p + COLS_MAX;       // 8

    count_kernel<<<NR, 64, 0, stream>>>(adj, cnt);
    scan_kernel<<<1, 1024, 0, stream>>>(cnt, rowptr);
    fill_kernel<<<NR, 64, 0, stream>>>(adj, rowptr, cols);
    level_kernel<<<1, 1024, 0, stream>>>(rowptr, cols, level);
    sort_kernel<<<1, 1024, 0, stream>>>(level, cnt, perm, inv, lev_p, cnt_p, meta);
    scan_kernel<<<1, 1024, 0, stream>>>(cnt_p, rowptr_p);
    trans_kernel<<<16, 256, 0, stream>>>(perm, rowptr, cols, inv, rowptr_p, cols_p);
    coef_kernel<<<16, 256, 0, stream>>>(perm, raw_n, raw_q, raw_p, width, length,
                                        slope, x_stor, c1p, c2p, c3p, c4p);
    route_kernel<<<1, 1024, 0, stream>>>(q_prime, c1p, c2p, c3p, c4p, rowptr_p,
                                         cols_p, lev_p, perm, meta, out);
}